// Round 5
// baseline (151.233 us; speedup 1.0000x reference)
//
#include <hip/hip_runtime.h>

// B=4, C=256, N=4096 attention modulation.
// out[b,c,i] = newL[b,i]*src[b,c,i] + newB[b,i],
// newL[b,i] = sum_j softmax_j(E)*oldL[j], E = src_i . ref_j over C.
//
// R17 (post-mortem of R16: flash 68us regression = vmcnt entanglement --
// lam/bet as 4 global partial loads per tile forced vmcnt waits that also
// drained the global_load_lds prefetch (vmcnt is ordered), serializing the
// double buffer. Fix + prep shrink):
//  (a) flash: back to 16 single-tile phases (2x16KB dbuf, R12's proven
//      loop). oldL/oldB partials summed ONCE per block into LDS (4KB,
//      bias folded); per-tile lam/bet are ds_read (lgkmcnt) -> fully
//      decoupled from the DMA vmcnt stream (this hazard existed in R12
//      too, where lam was a global load).
//  (b) flash builds A-fragments from fp32 src directly (R13's verified
//      pattern: 128 loads of 2x128B segments, once per wave, amortized
//      over 16 tiles) -> prep's 4 src z-slices die; prep = ref only
//      (grid z=4): transpose->r16 + fused conv partials + z==0 zeroing.
//  (c) flash accumulates sumP/sumL/sumB via atomicAdd (tail-end, small).
//  (d) post: 1024 blocks, 3 float4 partial reads (kept from R16).

#define B_ 4
#define C_ 256
#define N_ 4096
#define LOG2E 1.44269504f
#define SHIFT2 86.5617f      // 60 * log2(e)
#define JSLICE 8
#define BN_ (B_ * N_)
#define NT_ 16               // j-tiles per block (512 j)

typedef _Float16 half_t;
typedef _Float16 v8h  __attribute__((ext_vector_type(8)));
typedef float    v16f __attribute__((ext_vector_type(16)));

#define GLDS16(g, l) __builtin_amdgcn_global_load_lds(                         \
    (const __attribute__((address_space(1))) void*)(g),                        \
    (__attribute__((address_space(3))) void*)(l), 16, 0, 0)

// --------------------- prep: ref transpose to fp16 fragments + fused conv
// grid (N/64, C/64, B), block 256.
// fragment layout r16[b][tile=n/32][kb=c/16][lane][e],
//   lane=((c>>3)&1)*32+(n&31), e=c&7.
// conv: partial over this block's 64 channels -> non-atomic
// oldLp/oldBp[cgroup=blockIdx.y][b][n]. z==0 blocks zero the sum accums.
__global__ void k_prep(const float* __restrict__ ref,
                       const float* __restrict__ wl,
                       const float* __restrict__ wb,
                       half_t* __restrict__ r16,
                       float* __restrict__ oldLp, float* __restrict__ oldBp,
                       float* __restrict__ sums /* 3*BN, zeroed here */) {
    __shared__ float tile[64][65];
    __shared__ float red[8][64];
    int b  = blockIdx.z;
    int c0 = blockIdx.y * 64;
    int n0 = blockIdx.x * 64;
    int tid = threadIdx.x;
    if (b == 0) {                        // zero sum accumulators (race-free:
        int gid = (blockIdx.y * 64 + blockIdx.x) * 256 + tid;  // flash runs later)
        if (gid < 3 * BN_) sums[gid] = 0.f;
    }
    int tx = tid & 15, ty = tid >> 4;
#pragma unroll
    for (int q = 0; q < 4; q++) {
        int c = ty + q * 16;
        float4 v = *(const float4*)(ref + ((size_t)b * C_ + c0 + c) * N_ + n0 + tx * 4);
        tile[c][tx * 4 + 0] = v.x;
        tile[c][tx * 4 + 1] = v.y;
        tile[c][tx * 4 + 2] = v.z;
        tile[c][tx * 4 + 3] = v.w;
    }
    __syncthreads();
    // fragment write
    int r   = tid & 31;
    int lhi = (tid >> 5) & 1;
    int wv  = tid >> 6;                  // kb_local 0..3
#pragma unroll
    for (int nt = 0; nt < 2; nt++) {
        int nl = nt * 32 + r;
        v8h o;
#pragma unroll
        for (int e = 0; e < 8; e++)
            o[e] = (half_t)tile[wv * 16 + lhi * 8 + e][nl];
        size_t tj = (size_t)(n0 >> 5) + nt;
        size_t kb = (size_t)(c0 >> 4) + wv;
        *(v8h*)(r16 + ((((size_t)b * 128 + tj) * 16 + kb) * 64 + (tid & 63)) * 8) = o;
    }
    // fused 1x1-conv partial over this block's 64 channels (non-atomic)
    int n  = tid & 63;
    int cq = tid >> 6;                   // 0..3
    float aL = 0.f, aB = 0.f;
#pragma unroll
    for (int c = 0; c < 16; c++) {
        float v = tile[cq * 16 + c][n];
        aL += v * wl[c0 + cq * 16 + c];
        aB += v * wb[c0 + cq * 16 + c];
    }
    red[cq][n]     = aL;
    red[4 + cq][n] = aB;
    __syncthreads();
    size_t slot = ((size_t)blockIdx.y * B_ + b) * N_ + n0;
    if (tid < 64) {
        oldLp[slot + tid] = red[0][tid] + red[1][tid] + red[2][tid] + red[3][tid];
    } else if (tid < 128) {
        int u = tid - 64;
        oldBp[slot + u] = red[4][u] + red[5][u] + red[6][u] + red[7][u];
    }
}

// ------------------------------------------------------------------ flash
// grid 512 = B(4) x jslice(8) x iblock(16), block 512 = 8 waves.
// Wave owns 32 i-rows; A-fragments built from fp32 src (once per wave,
// 2x128B segments per load). oldL/oldB finalized into LDS at block start
// (ds_read per tile -- no vmcnt coupling with the DMA prefetch).
// 16 single-tile phases, 2x16KB double buffer via global_load_lds.
__global__ __launch_bounds__(512, 2) void k_flash(
        const float* __restrict__ src, const half_t* __restrict__ rT,
        const float* __restrict__ oldLp, const float* __restrict__ oldBp,
        const float* __restrict__ bl, const float* __restrict__ bb,
        float* __restrict__ sumP, float* __restrict__ sumL,
        float* __restrict__ sumB) {
    __shared__ half_t lds[2][8192];      // 2 x 16KB
    __shared__ float oL[512], oB[512];
    int bid    = blockIdx.x;
    int b      = bid & 3;                // XCD spread
    int jslice = (bid >> 2) & (JSLICE - 1);
    int iblock = bid >> 5;
    int tid    = threadIdx.x;
    int wv     = tid >> 6;               // 0..7
    int lane   = tid & 63;
    int l31    = lane & 31, lhi = lane >> 5;
    int ti     = iblock * 8 + wv;        // 32-row A tile index
    int i0     = ti * 32;
    int j0     = jslice * (N_ / JSLICE); // 512 j per block
    int tj0    = j0 >> 5;

    // A fragments from fp32 src: a[kb][e] = src[b][kb*16+lhi*8+e][i0+l31]
    // * log2e. 128 loads of 2x128B coalesced segments, once per wave.
    const float* aS = src + (size_t)b * C_ * N_ + i0 + l31;
    v8h a[16];
#pragma unroll
    for (int kb = 0; kb < 16; kb++) {
        v8h o;
#pragma unroll
        for (int e = 0; e < 8; e++)
            o[e] = (half_t)(aS[(size_t)(kb * 16 + lhi * 8 + e) * N_] * LOG2E);
        a[kb] = o;
    }

    // oldL/oldB: sum 4 conv partials + bias once into LDS (coalesced).
    {
        float accL = bl[0], accB = bb[0];
        size_t base = (size_t)b * N_ + j0 + tid;
#pragma unroll
        for (int g = 0; g < 4; g++) {
            accL += oldLp[(size_t)g * BN_ + base];
            accB += oldBp[(size_t)g * BN_ + base];
        }
        oL[tid] = accL;
        oB[tid] = accB;
    }

    const half_t* bBase = rT + (((size_t)b * 128 + tj0) * 16) * 512;  // block-uniform

    float sp[16], sl[16], sb[16];
#pragma unroll
    for (int r = 0; r < 16; r++) { sp[r] = 0.f; sl[r] = 0.f; sb[r] = 0.f; }

    // Prologue: DMA tile 0 into buffer 0. Wave wv covers chunks {wv, wv+8}.
#pragma unroll
    for (int q = 0; q < 2; q++) {
        int chunk = q * 8 + wv;
        GLDS16(bBase + (size_t)chunk * 512 + (size_t)lane * 8,
               &lds[0][(size_t)chunk * 512]);
    }

    for (int jt = 0; jt < NT_; jt++) {
        __syncthreads();                       // drains DMA -> buf[jt&1] ready
        if (jt + 1 < NT_) {                    // DMA next tile into other buffer
            const half_t* g = bBase + (size_t)(jt + 1) * 8192;
#pragma unroll
            for (int q = 0; q < 2; q++) {
                int chunk = q * 8 + wv;
                GLDS16(g + (size_t)chunk * 512 + (size_t)lane * 8,
                       &lds[(jt + 1) & 1][(size_t)chunk * 512]);
            }
        }
        const half_t* bt = lds[jt & 1] + (size_t)lane * 8;
        float lam = oL[jt * 32 + l31];         // ds_read: lgkm, not vmcnt
        float bet = oB[jt * 32 + l31];
        // Two independent 8-deep MFMA chains (halve the acc-dependency path).
        v16f acc0, acc1;
#pragma unroll
        for (int r = 0; r < 16; r++) { acc0[r] = -SHIFT2; acc1[r] = 0.f; }
#pragma unroll
        for (int kb = 0; kb < 8; kb++) {
            acc0 = __builtin_amdgcn_mfma_f32_32x32x16_f16(
                a[kb],     *(const v8h*)(bt + (size_t)kb * 512),       acc0, 0, 0, 0);
            acc1 = __builtin_amdgcn_mfma_f32_32x32x16_f16(
                a[kb + 8], *(const v8h*)(bt + (size_t)(kb + 8) * 512), acc1, 0, 0, 0);
        }
#pragma unroll
        for (int r = 0; r < 16; r++) {
            float p = __builtin_amdgcn_exp2f(acc0[r] + acc1[r]);
            sp[r] += p;
            sl[r] += p * lam;
            sb[r] += p * bet;
        }
    }

#pragma unroll
    for (int r = 0; r < 16; r++) {
        float tp = sp[r], tl = sl[r], tb = sb[r];
#pragma unroll
        for (int m = 1; m <= 16; m <<= 1) {
            tp += __shfl_xor(tp, m, 64);
            tl += __shfl_xor(tl, m, 64);
            tb += __shfl_xor(tb, m, 64);
        }
        if (l31 == 0) {
            // C/D layout: row = (reg&3) + 8*(reg>>2) + 4*(lane>>5)
            int row = (r & 3) + 8 * (r >> 2) + 4 * lhi;
            size_t ig = (size_t)b * N_ + i0 + row;
            atomicAdd(&sumP[ig], tp);
            atomicAdd(&sumL[ig], tl);
            atomicAdd(&sumB[ig], tb);
        }
    }
}

// ------------------------- epilogue: normalize + modulate
// grid (B, N/1024, C/4) = 1024 blocks, block 256. Thread owns 4
// consecutive pixels x 4 channels; newL/newB one float4 per sum array.
__global__ void k_post(const float* __restrict__ src,
                       const float* __restrict__ sums,
                       float* __restrict__ out) {
    int b  = blockIdx.x;
    int n0 = blockIdx.y * 1024;
    int c0 = blockIdx.z * 4;
    int t  = threadIdx.x;
    size_t bn = (size_t)b * N_ + n0 + t * 4;
    float4 sp = *(const float4*)(sums + bn);
    float4 sl = *(const float4*)(sums + BN_ + bn);
    float4 sb = *(const float4*)(sums + 2 * BN_ + bn);
    float4 L, T;
    L.x = sl.x / sp.x; L.y = sl.y / sp.y; L.z = sl.z / sp.z; L.w = sl.w / sp.w;
    T.x = sb.x / sp.x; T.y = sb.y / sp.y; T.z = sb.z / sp.z; T.w = sb.w / sp.w;
    const float* sp0 = src + ((size_t)b * C_ + c0) * N_ + n0 + t * 4;
    float*       op0 = out + ((size_t)b * C_ + c0) * N_ + n0 + t * 4;
#pragma unroll
    for (int c = 0; c < 4; c++) {
        float4 v = *(const float4*)(sp0 + (size_t)c * N_);
        float4 o;
        o.x = L.x * v.x + T.x;
        o.y = L.y * v.y + T.y;
        o.z = L.z * v.z + T.z;
        o.w = L.w * v.w + T.w;
        *(float4*)(op0 + (size_t)c * N_) = o;
    }
}

extern "C" void kernel_launch(void* const* d_in, const int* in_sizes, int n_in,
                              void* d_out, int out_size, void* d_ws, size_t ws_size,
                              hipStream_t stream) {
    const float* src = (const float*)d_in[0];
    const float* ref = (const float*)d_in[1];
    const float* wl  = (const float*)d_in[2];
    const float* bl  = (const float*)d_in[3];
    const float* wb  = (const float*)d_in[4];
    const float* bb  = (const float*)d_in[5];
    float* out = (float*)d_out;

    float* oldLp = (float*)d_ws;            // [4][B][N] conv partials
    float* oldBp = oldLp + 4 * BN_;         // [4][B][N]
    float* sums  = oldBp + 4 * BN_;         // sumP|sumL|sumB, 3*BN
    float* sumP  = sums;
    float* sumL  = sums + BN_;
    float* sumB  = sums + 2 * BN_;
    size_t needF  = (size_t)11 * BN_ * sizeof(float);
    size_t need16 = (size_t)B_ * N_ * C_ * sizeof(half_t);
    half_t* r16;
    if (ws_size >= needF + need16) r16 = (half_t*)((char*)d_ws + needF);
    else                           r16 = (half_t*)d_out;   // dead before k_post writes

    k_prep<<<dim3(N_ / 64, C_ / 64, B_), 256, 0, stream>>>(
        ref, wl, wb, r16, oldLp, oldBp, sums);
    k_flash<<<B_ * JSLICE * 16, 512, 0, stream>>>(
        src, r16, oldLp, oldBp, bl, bb, sumP, sumL, sumB);
    k_post<<<dim3(B_, N_ / 1024, C_ / 4), 256, 0, stream>>>(src, sums, out);
}

// Round 6
// 146.748 us; speedup vs baseline: 1.0306x; 1.0306x over previous
//
#include <hip/hip_runtime.h>

// B=4, C=256, N=4096 attention modulation.
// out[b,c,i] = newL[b,i]*src[b,c,i] + newB[b,i],
// newL[b,i] = sum_j softmax_j(E)*oldL[j], E = src_i . ref_j over C.
//
// R18: flash is R12-verbatim (the only 51.5us flash) with ONE structural
// change: the 16 __syncthreads (each lowering to s_waitcnt vmcnt(0) +
// s_barrier, draining the in-flight 16KB prefetch every phase) are
// replaced by raw s_barrier + counted vmcnt (T3/T4): 3-buffer LDS
// rotation, DMA(jt+2) issued after barrier(jt) (write target == buffer
// last read at jt-1; all waves past barrier(jt) are done with it), and
// s_waitcnt vmcnt(2) per phase (vmcnt(0) only at the last tile). lam/bet
// come from a 4KB LDS prologue so they're lgkm-domain and never enter the
// counted vmcnt stream (R16's entanglement lesson). part[] stores kept
// (no atomics -- untested suspect from R16/R17).
// Remainder: prep R12-verbatim (9 slices, finalized oldL/oldB); new
// k_comb collapses the 8 part slices -> final newL/newT once (1.5MB,
// L2-hot), so k_post is the verified fast form (2 float4 + 4-ch sweep).

#define B_ 4
#define C_ 256
#define N_ 4096
#define LOG2E 1.44269504f
#define SHIFT2 86.5617f      // 60 * log2(e)
#define JSLICE 8
#define BN_ (B_ * N_)
#define NT_ 16               // j-tiles per block (512 j)
#define NBUF 3               // rotating LDS tile buffers

typedef _Float16 half_t;
typedef _Float16 v8h  __attribute__((ext_vector_type(8)));
typedef float    v16f __attribute__((ext_vector_type(16)));

#define GLDS16(g, l) __builtin_amdgcn_global_load_lds(                         \
    (const __attribute__((address_space(1))) void*)(g),                        \
    (__attribute__((address_space(3))) void*)(l), 16, 0, 0)

// --------------------------------------------- prep: transpose + old lambda
// grid (N/64, C/64, 9), block 256.  (R12 verbatim)
// z in [0,8): fp32 [B][C][N] -> fp16 fragment-tiled
//   t16[b][tile=n/32][kb=c/16][lane][e], lane=((c>>3)&1)*32+(n&31), e=c&7;
//   src (z<4) additionally scaled by log2(e).
// z == 8: oldL/oldB = 1x1 conv on ref (b = blockIdx.y, n0 = blockIdx.x*64).
__global__ void k_prep(const float* __restrict__ src,
                       const float* __restrict__ ref,
                       const float* __restrict__ wl, const float* __restrict__ bl,
                       const float* __restrict__ wb, const float* __restrict__ bb,
                       half_t* __restrict__ s16, half_t* __restrict__ r16,
                       float* __restrict__ oldL, float* __restrict__ oldB) {
    if (blockIdx.z == 8) {
        int b  = blockIdx.y;
        int n0 = blockIdx.x * 64;
        int nl = threadIdx.x & 63;
        int cq = threadIdx.x >> 6;           // 0..3
        const float* p = ref + ((size_t)b * C_ + cq * 64) * N_ + n0 + nl;
        float aL = 0.f, aB = 0.f;
#pragma unroll 8
        for (int c = 0; c < 64; c++) {
            float v = p[(size_t)c * N_];
            aL += v * wl[cq * 64 + c];
            aB += v * wb[cq * 64 + c];
        }
        __shared__ float red[8][64];
        red[cq][nl]     = aL;
        red[4 + cq][nl] = aB;
        __syncthreads();
        if (threadIdx.x < 64) {
            int t = threadIdx.x;
            oldL[(size_t)b * N_ + n0 + t] =
                red[0][t] + red[1][t] + red[2][t] + red[3][t] + bl[0];
        } else if (threadIdx.x < 128) {
            int t = threadIdx.x - 64;
            oldB[(size_t)b * N_ + n0 + t] =
                red[4][t] + red[5][t] + red[6][t] + red[7][t] + bb[0];
        }
        return;
    }
    __shared__ float tile[64][65];
    int z  = blockIdx.z;
    int b  = z & 3;
    const float* in  = (z < B_) ? src : ref;
    half_t*      out = (z < B_) ? s16 : r16;
    float scale      = (z < B_) ? LOG2E : 1.0f;
    int c0 = blockIdx.y * 64;
    int n0 = blockIdx.x * 64;
    int tx = threadIdx.x & 15, ty = threadIdx.x >> 4;
#pragma unroll
    for (int q = 0; q < 4; q++) {
        int c = ty + q * 16;
        float4 v = *(const float4*)(in + ((size_t)b * C_ + c0 + c) * N_ + n0 + tx * 4);
        tile[c][tx * 4 + 0] = v.x;
        tile[c][tx * 4 + 1] = v.y;
        tile[c][tx * 4 + 2] = v.z;
        tile[c][tx * 4 + 3] = v.w;
    }
    __syncthreads();
    int r   = threadIdx.x & 31;
    int lhi = (threadIdx.x >> 5) & 1;
    int wv  = threadIdx.x >> 6;          // kb_local 0..3
#pragma unroll
    for (int nt = 0; nt < 2; nt++) {
        int nl = nt * 32 + r;
        v8h o;
#pragma unroll
        for (int e = 0; e < 8; e++)
            o[e] = (half_t)(tile[wv * 16 + lhi * 8 + e][nl] * scale);
        size_t tj = (size_t)(n0 >> 5) + nt;
        size_t kb = (size_t)(c0 >> 4) + wv;
        *(v8h*)(out + ((((size_t)b * 128 + tj) * 16 + kb) * 64 + (threadIdx.x & 63)) * 8) = o;
    }
}

// ------------------------------------------------------------------ flash
// grid 512 = B(4) x jslice(8) x iblock(16), block 512 = 8 waves.
// R12 compute verbatim; staging pipeline: 3 rotating 16KB buffers,
// raw s_barrier + counted vmcnt (prefetch never drained in the loop).
__global__ __launch_bounds__(512, 2) void k_flash(
        const half_t* __restrict__ sT, const half_t* __restrict__ rT,
        const float* __restrict__ oldL, const float* __restrict__ oldB,
        float* __restrict__ part /* [JSLICE][3][B*N] */) {
    __shared__ half_t lds[NBUF][8192];   // 3 x 16KB rotating
    __shared__ float oL[512], oB[512];
    int bid    = blockIdx.x;
    int b      = bid & 3;                // XCD spread
    int jslice = (bid >> 2) & (JSLICE - 1);
    int iblock = bid >> 5;
    int tid    = threadIdx.x;
    int wv     = tid >> 6;               // 0..7
    int lane   = tid & 63;
    int l31    = lane & 31, lhi = lane >> 5;
    int ti     = iblock * 8 + wv;        // 32-row A tile index
    int i0     = ti * 32;
    int j0     = jslice * (N_ / JSLICE); // 512 j per block
    int tj0    = j0 >> 5;

    // A fragments: one coalesced 1KB load per kb, held in VGPRs all kernel.
    const half_t* aP = sT + (((size_t)b * 128 + ti) * 16) * 512 + (size_t)lane * 8;
    v8h a[16];
#pragma unroll
    for (int kb = 0; kb < 16; kb++) a[kb] = *(const v8h*)(aP + (size_t)kb * 512);

    // lam/bet for this block's 512 j -> LDS (lgkm domain; keeps the
    // counted vmcnt stream pure GLDS).
    oL[tid] = oldL[(size_t)b * N_ + j0 + tid];
    oB[tid] = oldB[(size_t)b * N_ + j0 + tid];

    const half_t* bBase = rT + (((size_t)b * 128 + tj0) * 16) * 512;  // block-uniform

    float sp[16], sl[16], sb[16];
#pragma unroll
    for (int r = 0; r < 16; r++) { sp[r] = 0.f; sl[r] = 0.f; sb[r] = 0.f; }

    // Prologue: DMA tiles 0,1. Wave wv covers chunks {wv, wv+8}.
#pragma unroll
    for (int t = 0; t < 2; t++)
#pragma unroll
        for (int q = 0; q < 2; q++) {
            int chunk = q * 8 + wv;
            GLDS16(bBase + (size_t)t * 8192 + (size_t)chunk * 512 + (size_t)lane * 8,
                   &lds[t][(size_t)chunk * 512]);
        }
    __syncthreads();   // oL/oB visible; drains tiles 0,1 (one-time cost)

    for (int jt = 0; jt < NT_; jt++) {
        // Tile jt's chunks complete: each wave waits its own 2; the
        // barrier extends the guarantee to all 16 chunks. Outstanding at
        // this point <= {jt, jt+1} = 4 ops; vmcnt(2) leaves jt+1 in
        // flight (never drain to 0 mid-loop).
        if (jt < NT_ - 1) asm volatile("s_waitcnt vmcnt(2)" ::: "memory");
        else              asm volatile("s_waitcnt vmcnt(0)" ::: "memory");
        __builtin_amdgcn_s_barrier();
        __builtin_amdgcn_sched_barrier(0);
        // DMA tile jt+2 into buf[(jt+2)%3] == buffer last read at jt-1;
        // all waves passed barrier(jt) => done reading it. Never the
        // buffer being read this phase ((jt+2)%3 != jt%3).
        if (jt + 2 < NT_) {
            const half_t* g = bBase + (size_t)(jt + 2) * 8192;
            half_t* dst = &lds[(jt + 2) % NBUF][0];
#pragma unroll
            for (int q = 0; q < 2; q++) {
                int chunk = q * 8 + wv;
                GLDS16(g + (size_t)chunk * 512 + (size_t)lane * 8,
                       dst + (size_t)chunk * 512);
            }
        }
        const half_t* bt = &lds[jt % NBUF][0] + (size_t)lane * 8;
        float lam = oL[jt * 32 + l31];       // ds_read: lgkm, not vmcnt
        float bet = oB[jt * 32 + l31];
        // Two independent 8-deep MFMA chains (halve the acc-dependency path).
        v16f acc0, acc1;
#pragma unroll
        for (int r = 0; r < 16; r++) { acc0[r] = -SHIFT2; acc1[r] = 0.f; }
#pragma unroll
        for (int kb = 0; kb < 8; kb++) {
            acc0 = __builtin_amdgcn_mfma_f32_32x32x16_f16(
                a[kb],     *(const v8h*)(bt + (size_t)kb * 512),       acc0, 0, 0, 0);
            acc1 = __builtin_amdgcn_mfma_f32_32x32x16_f16(
                a[kb + 8], *(const v8h*)(bt + (size_t)(kb + 8) * 512), acc1, 0, 0, 0);
        }
#pragma unroll
        for (int r = 0; r < 16; r++) {
            float p = __builtin_amdgcn_exp2f(acc0[r] + acc1[r]);
            sp[r] += p;
            sl[r] += p * lam;
            sb[r] += p * bet;
        }
    }

    float* pSP = part + ((size_t)jslice * 3 + 0) * BN_;
    float* pSL = part + ((size_t)jslice * 3 + 1) * BN_;
    float* pSB = part + ((size_t)jslice * 3 + 2) * BN_;
#pragma unroll
    for (int r = 0; r < 16; r++) {
        float tp = sp[r], tl = sl[r], tb = sb[r];
#pragma unroll
        for (int m = 1; m <= 16; m <<= 1) {
            tp += __shfl_xor(tp, m, 64);
            tl += __shfl_xor(tl, m, 64);
            tb += __shfl_xor(tb, m, 64);
        }
        if (l31 == 0) {
            // C/D layout: row = (reg&3) + 8*(reg>>2) + 4*(lane>>5)
            int row = (r & 3) + 8 * (r >> 2) + 4 * lhi;
            size_t ig = (size_t)b * N_ + i0 + row;
            pSP[ig] = tp; pSL[ig] = tl; pSB[ig] = tb;
        }
    }
}

// --------------------- comb: collapse 8 part slices -> final newL/newT
// grid 64, block 256. part is L2-hot from flash; 1.5MB read, 128KB write.
__global__ void k_comb(const float* __restrict__ part,
                       float* __restrict__ newLT /* [2][B*N] */) {
    int g = blockIdx.x * 256 + threadIdx.x;    // 0 .. BN-1
    float sp = 0.f, sl = 0.f, sb = 0.f;
#pragma unroll
    for (int s = 0; s < JSLICE; s++) {
        sp += part[((size_t)s * 3 + 0) * BN_ + g];
        sl += part[((size_t)s * 3 + 1) * BN_ + g];
        sb += part[((size_t)s * 3 + 2) * BN_ + g];
    }
    newLT[g]       = sl / sp;
    newLT[BN_ + g] = sb / sp;
}

// ------------------------- epilogue: modulate
// grid (B, N/1024, C/4) = 1024 blocks, block 256. Thread owns 4
// consecutive pixels x 4 channels; L/T one float4 each (division already
// done in k_comb).
__global__ void k_post(const float* __restrict__ src,
                       const float* __restrict__ newLT,
                       float* __restrict__ out) {
    int b  = blockIdx.x;
    int n0 = blockIdx.y * 1024;
    int c0 = blockIdx.z * 4;
    int t  = threadIdx.x;
    size_t bn = (size_t)b * N_ + n0 + t * 4;
    float4 L = *(const float4*)(newLT + bn);
    float4 T = *(const float4*)(newLT + BN_ + bn);
    const float* sp0 = src + ((size_t)b * C_ + c0) * N_ + n0 + t * 4;
    float*       op0 = out + ((size_t)b * C_ + c0) * N_ + n0 + t * 4;
#pragma unroll
    for (int c = 0; c < 4; c++) {
        float4 v = *(const float4*)(sp0 + (size_t)c * N_);
        float4 o;
        o.x = L.x * v.x + T.x;
        o.y = L.y * v.y + T.y;
        o.z = L.z * v.z + T.z;
        o.w = L.w * v.w + T.w;
        *(float4*)(op0 + (size_t)c * N_) = o;
    }
}

extern "C" void kernel_launch(void* const* d_in, const int* in_sizes, int n_in,
                              void* d_out, int out_size, void* d_ws, size_t ws_size,
                              hipStream_t stream) {
    const float* src = (const float*)d_in[0];
    const float* ref = (const float*)d_in[1];
    const float* wl  = (const float*)d_in[2];
    const float* bl  = (const float*)d_in[3];
    const float* wb  = (const float*)d_in[4];
    const float* bb  = (const float*)d_in[5];
    float* out = (float*)d_out;

    float* oldL  = (float*)d_ws;
    float* oldB  = oldL + BN_;
    float* part  = oldB + BN_;              // [JSLICE][3][BN]
    float* newLT = part + (size_t)3 * JSLICE * BN_;   // [2][BN]
    size_t needF  = ((size_t)2 + 3 * JSLICE + 2) * BN_ * sizeof(float);
    size_t need16 = (size_t)2 * B_ * N_ * C_ * sizeof(half_t);
    half_t* s16;
    if (ws_size >= needF + need16) s16 = (half_t*)((char*)d_ws + needF);
    else                           s16 = (half_t*)d_out;   // dead before k_post writes
    half_t* r16 = s16 + (size_t)B_ * N_ * C_;

    k_prep<<<dim3(N_ / 64, C_ / 64, 9), 256, 0, stream>>>(
        src, ref, wl, bl, wb, bb, s16, r16, oldL, oldB);
    k_flash<<<512, 512, 0, stream>>>(s16, r16, oldL, oldB, part);
    k_comb<<<BN_ / 256, 256, 0, stream>>>(part, newLT);
    k_post<<<dim3(B_, N_ / 1024, C_ / 4), 256, 0, stream>>>(src, newLT, out);
}

// Round 7
// 145.389 us; speedup vs baseline: 1.0402x; 1.0093x over previous
//
#include <hip/hip_runtime.h>

// B=4, C=256, N=4096 attention modulation.
// out[b,c,i] = newL[b,i]*src[b,c,i] + newB[b,i],
// newL[b,i] = sum_j softmax_j(E)*oldL[j], E = src_i . ref_j over C.
//
// R19 (post-mortem R18: counted-vmcnt null -> barrier-drain theory dead.
// Real stall: barrier locksteps waves into alternating MFMA-burst /
// VALU-burst phases, and in-wave overlap is impossible because ONE acc
// pair is reused every tile (finish(t) blocks chain(t+1)). Fix = T15
// double-pipeline: dual acc sets; finish of tile t-1 interleaved into
// tile t's MFMA chain (2 finish iters per MFMA pair, static indices).
// VGPR ~96->~190: 1 block/CU accepted -- the overlap is now in-wave.
// Everything else (prep 9-slice R12-verbatim, comb, fast post) = R18.

#define B_ 4
#define C_ 256
#define N_ 4096
#define LOG2E 1.44269504f
#define SHIFT2 86.5617f      // 60 * log2(e)
#define JSLICE 8
#define BN_ (B_ * N_)
#define NT_ 16               // j-tiles per block (512 j)

typedef _Float16 half_t;
typedef _Float16 v8h  __attribute__((ext_vector_type(8)));
typedef float    v16f __attribute__((ext_vector_type(16)));

#define GLDS16(g, l) __builtin_amdgcn_global_load_lds(                         \
    (const __attribute__((address_space(1))) void*)(g),                        \
    (__attribute__((address_space(3))) void*)(l), 16, 0, 0)

// One j-tile phase: barrier, prefetch next tile, MFMA chain into ACC0/ACC1,
// with the PREVIOUS tile's finish loop (exp + 3 FMA, regs FACC*/FLAM/FBET)
// interleaved 2 iters per MFMA pair. DO_FIN is compile-time.
#define TILE_SEC(T, ACC0, ACC1, LAM, BET, DO_FIN, FACC0, FACC1, FLAM, FBET)    \
  {                                                                            \
    __syncthreads();                                                           \
    if ((T) + 1 < NT_) {                                                       \
      const half_t* g = bBase + (size_t)((T) + 1) * 8192;                      \
      _Pragma("unroll")                                                        \
      for (int q = 0; q < 2; q++) {                                            \
        int chunk = q * 8 + wv;                                                \
        GLDS16(g + (size_t)chunk * 512 + (size_t)lane * 8,                     \
               &lds[((T) + 1) & 1][(size_t)chunk * 512]);                      \
      }                                                                        \
    }                                                                          \
    LAM = oLp[(T) * 32];                                                       \
    BET = oBp[(T) * 32];                                                       \
    const half_t* bt = lds[(T) & 1] + (size_t)lane * 8;                        \
    _Pragma("unroll")                                                          \
    for (int r = 0; r < 16; r++) { ACC0[r] = -SHIFT2; ACC1[r] = 0.f; }         \
    _Pragma("unroll")                                                          \
    for (int kb = 0; kb < 8; kb++) {                                           \
      ACC0 = __builtin_amdgcn_mfma_f32_32x32x16_f16(                           \
          a[kb], *(const v8h*)(bt + (size_t)kb * 512), ACC0, 0, 0, 0);         \
      ACC1 = __builtin_amdgcn_mfma_f32_32x32x16_f16(                           \
          a[kb + 8], *(const v8h*)(bt + (size_t)(kb + 8) * 512), ACC1, 0,0,0); \
      if (DO_FIN) {                                                            \
        _Pragma("unroll")                                                      \
        for (int rr = 2 * kb; rr < 2 * kb + 2; rr++) {                         \
          float p = __builtin_amdgcn_exp2f(FACC0[rr] + FACC1[rr]);             \
          sp[rr] += p; sl[rr] += p * FLAM; sb[rr] += p * FBET;                 \
        }                                                                      \
      }                                                                        \
    }                                                                          \
  }

// --------------------------------------------- prep: transpose + old lambda
// grid (N/64, C/64, 9), block 256.  (R12 verbatim)
__global__ void k_prep(const float* __restrict__ src,
                       const float* __restrict__ ref,
                       const float* __restrict__ wl, const float* __restrict__ bl,
                       const float* __restrict__ wb, const float* __restrict__ bb,
                       half_t* __restrict__ s16, half_t* __restrict__ r16,
                       float* __restrict__ oldL, float* __restrict__ oldB) {
    if (blockIdx.z == 8) {
        int b  = blockIdx.y;
        int n0 = blockIdx.x * 64;
        int nl = threadIdx.x & 63;
        int cq = threadIdx.x >> 6;           // 0..3
        const float* p = ref + ((size_t)b * C_ + cq * 64) * N_ + n0 + nl;
        float aL = 0.f, aB = 0.f;
#pragma unroll 8
        for (int c = 0; c < 64; c++) {
            float v = p[(size_t)c * N_];
            aL += v * wl[cq * 64 + c];
            aB += v * wb[cq * 64 + c];
        }
        __shared__ float red[8][64];
        red[cq][nl]     = aL;
        red[4 + cq][nl] = aB;
        __syncthreads();
        if (threadIdx.x < 64) {
            int t = threadIdx.x;
            oldL[(size_t)b * N_ + n0 + t] =
                red[0][t] + red[1][t] + red[2][t] + red[3][t] + bl[0];
        } else if (threadIdx.x < 128) {
            int t = threadIdx.x - 64;
            oldB[(size_t)b * N_ + n0 + t] =
                red[4][t] + red[5][t] + red[6][t] + red[7][t] + bb[0];
        }
        return;
    }
    __shared__ float tile[64][65];
    int z  = blockIdx.z;
    int b  = z & 3;
    const float* in  = (z < B_) ? src : ref;
    half_t*      out = (z < B_) ? s16 : r16;
    float scale      = (z < B_) ? LOG2E : 1.0f;
    int c0 = blockIdx.y * 64;
    int n0 = blockIdx.x * 64;
    int tx = threadIdx.x & 15, ty = threadIdx.x >> 4;
#pragma unroll
    for (int q = 0; q < 4; q++) {
        int c = ty + q * 16;
        float4 v = *(const float4*)(in + ((size_t)b * C_ + c0 + c) * N_ + n0 + tx * 4);
        tile[c][tx * 4 + 0] = v.x;
        tile[c][tx * 4 + 1] = v.y;
        tile[c][tx * 4 + 2] = v.z;
        tile[c][tx * 4 + 3] = v.w;
    }
    __syncthreads();
    int r   = threadIdx.x & 31;
    int lhi = (threadIdx.x >> 5) & 1;
    int wv  = threadIdx.x >> 6;          // kb_local 0..3
#pragma unroll
    for (int nt = 0; nt < 2; nt++) {
        int nl = nt * 32 + r;
        v8h o;
#pragma unroll
        for (int e = 0; e < 8; e++)
            o[e] = (half_t)(tile[wv * 16 + lhi * 8 + e][nl] * scale);
        size_t tj = (size_t)(n0 >> 5) + nt;
        size_t kb = (size_t)(c0 >> 4) + wv;
        *(v8h*)(out + ((((size_t)b * 128 + tj) * 16 + kb) * 64 + (threadIdx.x & 63)) * 8) = o;
    }
}

// ------------------------------------------------------------------ flash
// grid 512 = B(4) x jslice(8) x iblock(16), block 512 = 8 waves.
// R12 staging (2x16KB dbuf + __syncthreads) with T15 double-pipeline:
// tiles alternate accA/accB; finish(prev) interleaved into chain(cur).
__global__ __launch_bounds__(512, 2) void k_flash(
        const half_t* __restrict__ sT, const half_t* __restrict__ rT,
        const float* __restrict__ oldL, const float* __restrict__ oldB,
        float* __restrict__ part /* [JSLICE][3][B*N] */) {
    __shared__ half_t lds[2][8192];      // 2 x 16KB
    int bid    = blockIdx.x;
    int b      = bid & 3;                // XCD spread
    int jslice = (bid >> 2) & (JSLICE - 1);
    int iblock = bid >> 5;
    int tid    = threadIdx.x;
    int wv     = tid >> 6;               // 0..7
    int lane   = tid & 63;
    int l31    = lane & 31, lhi = lane >> 5;
    int ti     = iblock * 8 + wv;        // 32-row A tile index
    int i0     = ti * 32;
    int j0     = jslice * (N_ / JSLICE); // 512 j per block
    int tj0    = j0 >> 5;

    // A fragments: one coalesced 1KB load per kb, held in VGPRs all kernel.
    const half_t* aP = sT + (((size_t)b * 128 + ti) * 16) * 512 + (size_t)lane * 8;
    v8h a[16];
#pragma unroll
    for (int kb = 0; kb < 16; kb++) a[kb] = *(const v8h*)(aP + (size_t)kb * 512);

    const half_t* bBase = rT + (((size_t)b * 128 + tj0) * 16) * 512;  // block-uniform
    const float*  oLp = oldL + (size_t)b * N_ + j0 + l31;
    const float*  oBp = oldB + (size_t)b * N_ + j0 + l31;

    float sp[16], sl[16], sb[16];
#pragma unroll
    for (int r = 0; r < 16; r++) { sp[r] = 0.f; sl[r] = 0.f; sb[r] = 0.f; }

    // Prologue: DMA tile 0 into buffer 0. Wave wv covers chunks {wv, wv+8}.
#pragma unroll
    for (int q = 0; q < 2; q++) {
        int chunk = q * 8 + wv;
        GLDS16(bBase + (size_t)chunk * 512 + (size_t)lane * 8,
               &lds[0][(size_t)chunk * 512]);
    }

    v16f accA0, accA1, accB0, accB1;
    float lamA = 0.f, betA = 0.f, lamB = 0.f, betB = 0.f;

    // tile 0 -> A (no finish yet)
    TILE_SEC(0, accA0, accA1, lamA, betA, false, accB0, accB1, lamB, betB)
    // tiles 1..14: alternate B (finishing A) / A (finishing B)
    for (int pt = 0; pt < 7; pt++) {
        int t1 = 2 * pt + 1, t2 = 2 * pt + 2;
        TILE_SEC(t1, accB0, accB1, lamB, betB, true, accA0, accA1, lamA, betA)
        TILE_SEC(t2, accA0, accA1, lamA, betA, true, accB0, accB1, lamB, betB)
    }
    // tile 15 -> B, finishing A
    TILE_SEC(15, accB0, accB1, lamB, betB, true, accA0, accA1, lamA, betA)
    // tail: finish B
#pragma unroll
    for (int r = 0; r < 16; r++) {
        float p = __builtin_amdgcn_exp2f(accB0[r] + accB1[r]);
        sp[r] += p; sl[r] += p * lamB; sb[r] += p * betB;
    }

    float* pSP = part + ((size_t)jslice * 3 + 0) * BN_;
    float* pSL = part + ((size_t)jslice * 3 + 1) * BN_;
    float* pSB = part + ((size_t)jslice * 3 + 2) * BN_;
#pragma unroll
    for (int r = 0; r < 16; r++) {
        float tp = sp[r], tl = sl[r], tb = sb[r];
#pragma unroll
        for (int m = 1; m <= 16; m <<= 1) {
            tp += __shfl_xor(tp, m, 64);
            tl += __shfl_xor(tl, m, 64);
            tb += __shfl_xor(tb, m, 64);
        }
        if (l31 == 0) {
            // C/D layout: row = (reg&3) + 8*(reg>>2) + 4*(lane>>5)
            int row = (r & 3) + 8 * (r >> 2) + 4 * lhi;
            size_t ig = (size_t)b * N_ + i0 + row;
            pSP[ig] = tp; pSL[ig] = tl; pSB[ig] = tb;
        }
    }
}

// --------------------- comb: collapse 8 part slices -> final newL/newT
// grid 64, block 256. part is L2-hot from flash; 1.5MB read, 128KB write.
__global__ void k_comb(const float* __restrict__ part,
                       float* __restrict__ newLT /* [2][B*N] */) {
    int g = blockIdx.x * 256 + threadIdx.x;    // 0 .. BN-1
    float sp = 0.f, sl = 0.f, sb = 0.f;
#pragma unroll
    for (int s = 0; s < JSLICE; s++) {
        sp += part[((size_t)s * 3 + 0) * BN_ + g];
        sl += part[((size_t)s * 3 + 1) * BN_ + g];
        sb += part[((size_t)s * 3 + 2) * BN_ + g];
    }
    newLT[g]       = sl / sp;
    newLT[BN_ + g] = sb / sp;
}

// ------------------------- epilogue: modulate
// grid (B, N/1024, C/4) = 1024 blocks, block 256. Thread owns 4
// consecutive pixels x 4 channels; L/T one float4 each.
__global__ void k_post(const float* __restrict__ src,
                       const float* __restrict__ newLT,
                       float* __restrict__ out) {
    int b  = blockIdx.x;
    int n0 = blockIdx.y * 1024;
    int c0 = blockIdx.z * 4;
    int t  = threadIdx.x;
    size_t bn = (size_t)b * N_ + n0 + t * 4;
    float4 L = *(const float4*)(newLT + bn);
    float4 T = *(const float4*)(newLT + BN_ + bn);
    const float* sp0 = src + ((size_t)b * C_ + c0) * N_ + n0 + t * 4;
    float*       op0 = out + ((size_t)b * C_ + c0) * N_ + n0 + t * 4;
#pragma unroll
    for (int c = 0; c < 4; c++) {
        float4 v = *(const float4*)(sp0 + (size_t)c * N_);
        float4 o;
        o.x = L.x * v.x + T.x;
        o.y = L.y * v.y + T.y;
        o.z = L.z * v.z + T.z;
        o.w = L.w * v.w + T.w;
        *(float4*)(op0 + (size_t)c * N_) = o;
    }
}

extern "C" void kernel_launch(void* const* d_in, const int* in_sizes, int n_in,
                              void* d_out, int out_size, void* d_ws, size_t ws_size,
                              hipStream_t stream) {
    const float* src = (const float*)d_in[0];
    const float* ref = (const float*)d_in[1];
    const float* wl  = (const float*)d_in[2];
    const float* bl  = (const float*)d_in[3];
    const float* wb  = (const float*)d_in[4];
    const float* bb  = (const float*)d_in[5];
    float* out = (float*)d_out;

    float* oldL  = (float*)d_ws;
    float* oldB  = oldL + BN_;
    float* part  = oldB + BN_;              // [JSLICE][3][BN]
    float* newLT = part + (size_t)3 * JSLICE * BN_;   // [2][BN]
    size_t needF  = ((size_t)2 + 3 * JSLICE + 2) * BN_ * sizeof(float);
    size_t need16 = (size_t)2 * B_ * N_ * C_ * sizeof(half_t);
    half_t* s16;
    if (ws_size >= needF + need16) s16 = (half_t*)((char*)d_ws + needF);
    else                           s16 = (half_t*)d_out;   // dead before k_post writes
    half_t* r16 = s16 + (size_t)B_ * N_ * C_;

    k_prep<<<dim3(N_ / 64, C_ / 64, 9), 256, 0, stream>>>(
        src, ref, wl, bl, wb, bb, s16, r16, oldL, oldB);
    k_flash<<<512, 512, 0, stream>>>(s16, r16, oldL, oldB, part);
    k_comb<<<BN_ / 256, 256, 0, stream>>>(part, newLT);
    k_post<<<dim3(B_, N_ / 1024, C_ / 4), 256, 0, stream>>>(src, newLT, out);
}

// Round 8
// 144.803 us; speedup vs baseline: 1.0444x; 1.0041x over previous
//
#include <hip/hip_runtime.h>

// B=4, C=256, N=4096 attention modulation.
// out[b,c,i] = newL[b,i]*src[b,c,i] + newB[b,i],
// newL[b,i] = sum_j softmax_j(E)*oldL[j], E = src_i . ref_j over C.
//
// R20 (post-mortem R19: occupancy audit -- 184 total regs/wave = 2
// waves/SIMD = ONE 8-wave block per CU. Single barrier domain locksteps
// all resident waves into the same phase: LDS-burst, then MFMA-burst,
// then finish-burst => the three pipes SUM (cycle audit: 3.1k LDS + 2.2k
// MFMA + 1.2k VALU ~= 6.5k/tile ~= observed). Fix: TWO independent
// 4-wave blocks per CU (256 thr, same 8 waves/CU, same per-wave code) --
// two barrier domains drift out of phase, so one block's LDS burst
// overlaps the other's MFMA/finish. Cost: duplicate B staging per block
// (+8MB FETCH, L2-absorbed). Everything else R19-identical (T15
// dual-acc finish interleave, prep/comb/post verbatim).

#define B_ 4
#define C_ 256
#define N_ 4096
#define LOG2E 1.44269504f
#define SHIFT2 86.5617f      // 60 * log2(e)
#define JSLICE 8
#define BN_ (B_ * N_)
#define NT_ 16               // j-tiles per block (512 j)

typedef _Float16 half_t;
typedef _Float16 v8h  __attribute__((ext_vector_type(8)));
typedef float    v16f __attribute__((ext_vector_type(16)));

#define GLDS16(g, l) __builtin_amdgcn_global_load_lds(                         \
    (const __attribute__((address_space(1))) void*)(g),                        \
    (__attribute__((address_space(3))) void*)(l), 16, 0, 0)

// One j-tile phase: barrier, prefetch next tile (4 waves x 4 chunks),
// MFMA chain into ACC0/ACC1, with the PREVIOUS tile's finish loop
// (exp + 3 FMA) interleaved 2 iters per MFMA pair. DO_FIN compile-time.
#define TILE_SEC(T, ACC0, ACC1, LAM, BET, DO_FIN, FACC0, FACC1, FLAM, FBET)    \
  {                                                                            \
    __syncthreads();                                                           \
    if ((T) + 1 < NT_) {                                                       \
      const half_t* g = bBase + (size_t)((T) + 1) * 8192;                      \
      _Pragma("unroll")                                                        \
      for (int q = 0; q < 4; q++) {                                            \
        int chunk = q * 4 + wv;                                                \
        GLDS16(g + (size_t)chunk * 512 + (size_t)lane * 8,                     \
               &lds[((T) + 1) & 1][(size_t)chunk * 512]);                      \
      }                                                                        \
    }                                                                          \
    LAM = oLp[(T) * 32];                                                       \
    BET = oBp[(T) * 32];                                                       \
    const half_t* bt = lds[(T) & 1] + (size_t)lane * 8;                        \
    _Pragma("unroll")                                                          \
    for (int r = 0; r < 16; r++) { ACC0[r] = -SHIFT2; ACC1[r] = 0.f; }         \
    _Pragma("unroll")                                                          \
    for (int kb = 0; kb < 8; kb++) {                                           \
      ACC0 = __builtin_amdgcn_mfma_f32_32x32x16_f16(                           \
          a[kb], *(const v8h*)(bt + (size_t)kb * 512), ACC0, 0, 0, 0);         \
      ACC1 = __builtin_amdgcn_mfma_f32_32x32x16_f16(                           \
          a[kb + 8], *(const v8h*)(bt + (size_t)(kb + 8) * 512), ACC1, 0,0,0); \
      if (DO_FIN) {                                                            \
        _Pragma("unroll")                                                      \
        for (int rr = 2 * kb; rr < 2 * kb + 2; rr++) {                         \
          float p = __builtin_amdgcn_exp2f(FACC0[rr] + FACC1[rr]);             \
          sp[rr] += p; sl[rr] += p * FLAM; sb[rr] += p * FBET;                 \
        }                                                                      \
      }                                                                        \
    }                                                                          \
  }

// --------------------------------------------- prep: transpose + old lambda
// grid (N/64, C/64, 9), block 256.  (R12 verbatim)
__global__ void k_prep(const float* __restrict__ src,
                       const float* __restrict__ ref,
                       const float* __restrict__ wl, const float* __restrict__ bl,
                       const float* __restrict__ wb, const float* __restrict__ bb,
                       half_t* __restrict__ s16, half_t* __restrict__ r16,
                       float* __restrict__ oldL, float* __restrict__ oldB) {
    if (blockIdx.z == 8) {
        int b  = blockIdx.y;
        int n0 = blockIdx.x * 64;
        int nl = threadIdx.x & 63;
        int cq = threadIdx.x >> 6;           // 0..3
        const float* p = ref + ((size_t)b * C_ + cq * 64) * N_ + n0 + nl;
        float aL = 0.f, aB = 0.f;
#pragma unroll 8
        for (int c = 0; c < 64; c++) {
            float v = p[(size_t)c * N_];
            aL += v * wl[cq * 64 + c];
            aB += v * wb[cq * 64 + c];
        }
        __shared__ float red[8][64];
        red[cq][nl]     = aL;
        red[4 + cq][nl] = aB;
        __syncthreads();
        if (threadIdx.x < 64) {
            int t = threadIdx.x;
            oldL[(size_t)b * N_ + n0 + t] =
                red[0][t] + red[1][t] + red[2][t] + red[3][t] + bl[0];
        } else if (threadIdx.x < 128) {
            int t = threadIdx.x - 64;
            oldB[(size_t)b * N_ + n0 + t] =
                red[4][t] + red[5][t] + red[6][t] + red[7][t] + bb[0];
        }
        return;
    }
    __shared__ float tile[64][65];
    int z  = blockIdx.z;
    int b  = z & 3;
    const float* in  = (z < B_) ? src : ref;
    half_t*      out = (z < B_) ? s16 : r16;
    float scale      = (z < B_) ? LOG2E : 1.0f;
    int c0 = blockIdx.y * 64;
    int n0 = blockIdx.x * 64;
    int tx = threadIdx.x & 15, ty = threadIdx.x >> 4;
#pragma unroll
    for (int q = 0; q < 4; q++) {
        int c = ty + q * 16;
        float4 v = *(const float4*)(in + ((size_t)b * C_ + c0 + c) * N_ + n0 + tx * 4);
        tile[c][tx * 4 + 0] = v.x;
        tile[c][tx * 4 + 1] = v.y;
        tile[c][tx * 4 + 2] = v.z;
        tile[c][tx * 4 + 3] = v.w;
    }
    __syncthreads();
    int r   = threadIdx.x & 31;
    int lhi = (threadIdx.x >> 5) & 1;
    int wv  = threadIdx.x >> 6;          // kb_local 0..3
#pragma unroll
    for (int nt = 0; nt < 2; nt++) {
        int nl = nt * 32 + r;
        v8h o;
#pragma unroll
        for (int e = 0; e < 8; e++)
            o[e] = (half_t)(tile[wv * 16 + lhi * 8 + e][nl] * scale);
        size_t tj = (size_t)(n0 >> 5) + nt;
        size_t kb = (size_t)(c0 >> 4) + wv;
        *(v8h*)(out + ((((size_t)b * 128 + tj) * 16 + kb) * 64 + (threadIdx.x & 63)) * 8) = o;
    }
}

// ------------------------------------------------------------------ flash
// grid 1024 = B(4) x jslice(8) x iblock(32), block 256 = 4 waves.
// Two such blocks co-reside per CU (184 regs/wave, 2 waves/SIMD each) as
// INDEPENDENT barrier domains -> phase drift -> LDS/MFMA/VALU overlap.
// Per-wave code identical to R19 (T15 dual-acc interleave).
__global__ __launch_bounds__(256, 2) void k_flash(
        const half_t* __restrict__ sT, const half_t* __restrict__ rT,
        const float* __restrict__ oldL, const float* __restrict__ oldB,
        float* __restrict__ part /* [JSLICE][3][B*N] */) {
    __shared__ half_t lds[2][8192];      // 2 x 16KB
    int bid    = blockIdx.x;
    int b      = bid & 3;                // XCD spread
    int jslice = (bid >> 2) & (JSLICE - 1);
    int iblock = bid >> 5;               // 0..31
    int tid    = threadIdx.x;
    int wv     = tid >> 6;               // 0..3
    int lane   = tid & 63;
    int l31    = lane & 31, lhi = lane >> 5;
    int ti     = iblock * 4 + wv;        // 32-row A tile index (0..127)
    int i0     = ti * 32;
    int j0     = jslice * (N_ / JSLICE); // 512 j per block
    int tj0    = j0 >> 5;

    // A fragments: one coalesced 1KB load per kb, held in VGPRs all kernel.
    const half_t* aP = sT + (((size_t)b * 128 + ti) * 16) * 512 + (size_t)lane * 8;
    v8h a[16];
#pragma unroll
    for (int kb = 0; kb < 16; kb++) a[kb] = *(const v8h*)(aP + (size_t)kb * 512);

    const half_t* bBase = rT + (((size_t)b * 128 + tj0) * 16) * 512;  // block-uniform
    const float*  oLp = oldL + (size_t)b * N_ + j0 + l31;
    const float*  oBp = oldB + (size_t)b * N_ + j0 + l31;

    float sp[16], sl[16], sb[16];
#pragma unroll
    for (int r = 0; r < 16; r++) { sp[r] = 0.f; sl[r] = 0.f; sb[r] = 0.f; }

    // Prologue: DMA tile 0 into buffer 0. Wave wv covers 4 chunks.
#pragma unroll
    for (int q = 0; q < 4; q++) {
        int chunk = q * 4 + wv;
        GLDS16(bBase + (size_t)chunk * 512 + (size_t)lane * 8,
               &lds[0][(size_t)chunk * 512]);
    }

    v16f accA0, accA1, accB0, accB1;
    float lamA = 0.f, betA = 0.f, lamB = 0.f, betB = 0.f;

    // tile 0 -> A (no finish yet)
    TILE_SEC(0, accA0, accA1, lamA, betA, false, accB0, accB1, lamB, betB)
    // tiles 1..14: alternate B (finishing A) / A (finishing B)
    for (int pt = 0; pt < 7; pt++) {
        int t1 = 2 * pt + 1, t2 = 2 * pt + 2;
        TILE_SEC(t1, accB0, accB1, lamB, betB, true, accA0, accA1, lamA, betA)
        TILE_SEC(t2, accA0, accA1, lamA, betA, true, accB0, accB1, lamB, betB)
    }
    // tile 15 -> B, finishing A
    TILE_SEC(15, accB0, accB1, lamB, betB, true, accA0, accA1, lamA, betA)
    // tail: finish B
#pragma unroll
    for (int r = 0; r < 16; r++) {
        float p = __builtin_amdgcn_exp2f(accB0[r] + accB1[r]);
        sp[r] += p; sl[r] += p * lamB; sb[r] += p * betB;
    }

    float* pSP = part + ((size_t)jslice * 3 + 0) * BN_;
    float* pSL = part + ((size_t)jslice * 3 + 1) * BN_;
    float* pSB = part + ((size_t)jslice * 3 + 2) * BN_;
#pragma unroll
    for (int r = 0; r < 16; r++) {
        float tp = sp[r], tl = sl[r], tb = sb[r];
#pragma unroll
        for (int m = 1; m <= 16; m <<= 1) {
            tp += __shfl_xor(tp, m, 64);
            tl += __shfl_xor(tl, m, 64);
            tb += __shfl_xor(tb, m, 64);
        }
        if (l31 == 0) {
            // C/D layout: row = (reg&3) + 8*(reg>>2) + 4*(lane>>5)
            int row = (r & 3) + 8 * (r >> 2) + 4 * lhi;
            size_t ig = (size_t)b * N_ + i0 + row;
            pSP[ig] = tp; pSL[ig] = tl; pSB[ig] = tb;
        }
    }
}

// --------------------- comb: collapse 8 part slices -> final newL/newT
// grid 64, block 256. part is L2-hot from flash; 1.5MB read, 128KB write.
__global__ void k_comb(const float* __restrict__ part,
                       float* __restrict__ newLT /* [2][B*N] */) {
    int g = blockIdx.x * 256 + threadIdx.x;    // 0 .. BN-1
    float sp = 0.f, sl = 0.f, sb = 0.f;
#pragma unroll
    for (int s = 0; s < JSLICE; s++) {
        sp += part[((size_t)s * 3 + 0) * BN_ + g];
        sl += part[((size_t)s * 3 + 1) * BN_ + g];
        sb += part[((size_t)s * 3 + 2) * BN_ + g];
    }
    newLT[g]       = sl / sp;
    newLT[BN_ + g] = sb / sp;
}

// ------------------------- epilogue: modulate
// grid (B, N/1024, C/4) = 1024 blocks, block 256. Thread owns 4
// consecutive pixels x 4 channels; L/T one float4 each.
__global__ void k_post(const float* __restrict__ src,
                       const float* __restrict__ newLT,
                       float* __restrict__ out) {
    int b  = blockIdx.x;
    int n0 = blockIdx.y * 1024;
    int c0 = blockIdx.z * 4;
    int t  = threadIdx.x;
    size_t bn = (size_t)b * N_ + n0 + t * 4;
    float4 L = *(const float4*)(newLT + bn);
    float4 T = *(const float4*)(newLT + BN_ + bn);
    const float* sp0 = src + ((size_t)b * C_ + c0) * N_ + n0 + t * 4;
    float*       op0 = out + ((size_t)b * C_ + c0) * N_ + n0 + t * 4;
#pragma unroll
    for (int c = 0; c < 4; c++) {
        float4 v = *(const float4*)(sp0 + (size_t)c * N_);
        float4 o;
        o.x = L.x * v.x + T.x;
        o.y = L.y * v.y + T.y;
        o.z = L.z * v.z + T.z;
        o.w = L.w * v.w + T.w;
        *(float4*)(op0 + (size_t)c * N_) = o;
    }
}

extern "C" void kernel_launch(void* const* d_in, const int* in_sizes, int n_in,
                              void* d_out, int out_size, void* d_ws, size_t ws_size,
                              hipStream_t stream) {
    const float* src = (const float*)d_in[0];
    const float* ref = (const float*)d_in[1];
    const float* wl  = (const float*)d_in[2];
    const float* bl  = (const float*)d_in[3];
    const float* wb  = (const float*)d_in[4];
    const float* bb  = (const float*)d_in[5];
    float* out = (float*)d_out;

    float* oldL  = (float*)d_ws;
    float* oldB  = oldL + BN_;
    float* part  = oldB + BN_;              // [JSLICE][3][BN]
    float* newLT = part + (size_t)3 * JSLICE * BN_;   // [2][BN]
    size_t needF  = ((size_t)2 + 3 * JSLICE + 2) * BN_ * sizeof(float);
    size_t need16 = (size_t)2 * B_ * N_ * C_ * sizeof(half_t);
    half_t* s16;
    if (ws_size >= needF + need16) s16 = (half_t*)((char*)d_ws + needF);
    else                           s16 = (half_t*)d_out;   // dead before k_post writes
    half_t* r16 = s16 + (size_t)B_ * N_ * C_;

    k_prep<<<dim3(N_ / 64, C_ / 64, 9), 256, 0, stream>>>(
        src, ref, wl, bl, wb, bb, s16, r16, oldL, oldB);
    k_flash<<<B_ * JSLICE * 32, 256, 0, stream>>>(s16, r16, oldL, oldB, part);
    k_comb<<<BN_ / 256, 256, 0, stream>>>(part, newLT);
    k_post<<<dim3(B_, N_ / 1024, C_ / 4), 256, 0, stream>>>(src, newLT, out);
}